// Round 11
// baseline (331.249 us; speedup 1.0000x reference)
//
#include <hip/hip_runtime.h>
#include <hip/hip_bf16.h>

// FlatConv3x3NNUE R11: 25-way position parallelism. Each wave = (btile, position):
// 32 rows, ONE position, R6 inner body (reg-direct W, depth-1 wA/wB, in-register
// activations). 6400 waves -> 4x TLP vs R6. Partials: 25 planes, head sums 25.

#define BATCH 8192
#define CMAXF 0.9921875f
#define NPOS 25

// wf: bf16 [25 p][25 q][8 f][64 lane][8 j]  (8KB per phase, contiguous)
#define WF_TOTAL 2560000
#define PART_BYTE_OFF 5120000  // float [25][8192][32] partial features (26.2 MB)

using bf16x8 = __attribute__((ext_vector_type(8))) short;
using f32x4  = __attribute__((ext_vector_type(4))) float;

__device__ __forceinline__ unsigned short f2bf(float f) {
  union { float f; unsigned u; } v; v.f = f;
  unsigned u = v.u + 0x7fffu + ((v.u >> 16) & 1u);   // RNE
  return (unsigned short)(u >> 16);
}

__device__ __forceinline__ f32x4 mfma16(bf16x8 a, bf16x8 b, f32x4 c) {
  return __builtin_amdgcn_mfma_f32_16x16x32_bf16(a, b, c, 0, 0, 0);
}

// relu + pack f32x4 -> 2 u32 of bf16 pairs
__device__ __forceinline__ void relu_pack2(f32x4 v, unsigned& lo, unsigned& hi) {
  union { __hip_bfloat162 h; unsigned u; } a_, b_;
  a_.h = __float22bfloat162_rn(make_float2(fmaxf(v[0], 0.f), fmaxf(v[1], 0.f)));
  b_.h = __float22bfloat162_rn(make_float2(fmaxf(v[2], 0.f), fmaxf(v[3], 0.f)));
  lo = a_.u; hi = b_.u;
}

// ---------------- prep: weights -> bf16 [p][q][f][lane][j] (same as R5-R10) ------------
__global__ __launch_bounds__(256) void prep_kernel(
    const float* __restrict__ W1, const float* __restrict__ b1,
    const float* __restrict__ W2, const float* __restrict__ W3,
    const float* __restrict__ W4, unsigned short* __restrict__ wf)
{
  int e4 = (blockIdx.x * 256 + threadIdx.x) * 4;
  if (e4 >= WF_TOTAL) return;
  const int j0 = e4 & 7;
  const int l = (e4 >> 3) & 63;
  const int f = (e4 >> 9) & 7;
  const int pq = e4 >> 12;
  const int p = pq / 25, q = pq - p * 25;
  const int g = l >> 4, l15 = l & 15;
  unsigned short vv[4];
#pragma unroll
  for (int i = 0; i < 4; ++i) {
    int j = j0 + i;
    float val = 0.f;
    if (q < 20) {
      int s = q / 5, rem = q - s * 5;
      if (rem == 0) {              // L1(s): k = g*8+j (18 real, 18=bias)
        int o = f * 16 + l15;
        int kk = g * 8 + j;
        if (kk < 18) {
          int c = (kk >= 9) ? 1 : 0;
          int rr = kk - c * 9;
          int py = rr / 3, px = rr - py * 3;
          int si = s >> 1, sj = s & 1;
          int di = py - si, dj = px - sj;
          if (di >= 0 && di < 2 && dj >= 0 && dj < 2)
            val = W1[((p * 128 + o) * 2 + c) * 4 + di * 2 + dj];
        } else if (kk == 18) {
          val = b1[p * 128 + o];
        }
      } else {                     // L2(s,kq): c = 32kq + 16(j>>2) + 4g + (j&3)
        int kq = rem - 1;
        int o = f * 16 + l15;
        int c = kq * 32 + ((j >> 2) << 4) + g * 4 + (j & 3);
        val = W2[((p * 128 + o) * 128 + c) * 4 + s];
      }
    } else if (q < 24) {           // L3(kq)
      int kq = q - 20;
      int o = f * 16 + l15;
      int c = kq * 32 + ((j >> 2) << 4) + g * 4 + (j & 3);
      val = W3[(p * 128 + o) * 128 + c];
    } else {                       // L4: f = nt*4+kq
      int nt = f >> 2, kq = f & 3;
      int o = nt * 16 + l15;
      int c = kq * 32 + ((j >> 2) << 4) + g * 4 + (j & 3);
      val = W4[(p * 32 + o) * 128 + c];
    }
    vv[i] = f2bf(val);
  }
  ushort4 st; st.x = vv[0]; st.y = vv[1]; st.z = vv[2]; st.w = vv[3];
  *(ushort4*)(wf + e4) = st;
}

// B-frag (bf16x8) from 4 packed u32
#define BFRAG(pkm, kq) ({                                        \
  union { unsigned u[4]; bf16x8 v; } _bf;                        \
  _bf.u[0] = pkm[2*(kq)][0];   _bf.u[1] = pkm[2*(kq)][1];        \
  _bf.u[2] = pkm[2*(kq)+1][0]; _bf.u[3] = pkm[2*(kq)+1][1];      \
  _bf.v; })

// ---------------- tower: 1 wave/block, 1 position/wave, M=32, no barriers -------------
__global__ __launch_bounds__(64, 4) void tower_kernel(
    const float* __restrict__ x,
    const float* __restrict__ b2v, const float* __restrict__ b3v,
    const float* __restrict__ b4v,
    const unsigned short* __restrict__ wf, float* __restrict__ part)
{
  __shared__ __align__(16) unsigned short xsw[32 * 98];

  const int l = threadIdx.x;
  const int l15 = l & 15;
  const int g = l >> 4;

  // XCD-contiguous bijective remap: 6400 = 8 * 800; p varies fastest within an XCD
  int bid = blockIdx.x;
  int lin = (bid & 7) * 800 + (bid >> 3);
  int btile = lin / 25;          // 0..255
  const int p = lin - btile * 25; // 0..24
  const int R0 = btile * 32;

  bf16x8 wA[8], wB[8];

#define PRE(DST, QN)                                                              \
  {                                                                               \
    const unsigned short* s_ = wf + ((size_t)(p * 25 + (QN)) * 8) * 512 + l * 8;  \
    _Pragma("unroll")                                                             \
    for (int f_ = 0; f_ < 8; ++f_) DST[f_] = *(const bf16x8*)(s_ + f_ * 512);     \
  }

  // issue first W loads before xs fill so they are in flight during staging
  PRE(wA, 0);

  for (int idx = l; idx < 32 * 98; idx += 64)
    xsw[idx] = f2bf(x[(size_t)R0 * 98 + idx]);
  __syncthreads();

  // per-lane K decode for L1 B-fragment
  int kbase[8]; int kmode[8];   // 0: zero, 1: xs, 2: const one (bias)
#pragma unroll
  for (int j = 0; j < 8; ++j) {
    int k = g * 8 + j;
    if (k < 18) {
      int c = (k >= 9) ? 1 : 0;
      int rr = k - c * 9;
      int py = rr / 3, px = rr - (rr / 3) * 3;
      kbase[j] = c * 49 + py * 7 + px;
      kmode[j] = 1;
    } else { kbase[j] = 0; kmode[j] = (k == 18) ? 2 : 0; }
  }

  const f32x4 zf = {0.f, 0.f, 0.f, 0.f};
  const int y0 = p / 5;
  const int x0 = p - y0 * 5;
  const int poff = y0 * 7 + x0;

  // L1 B-fragments (both batch tiles) from xs
  bf16x8 a1x[2];
#pragma unroll
  for (int m = 0; m < 2; ++m) {
#pragma unroll
    for (int j = 0; j < 8; ++j) {
      unsigned short v = 0;
      if (kmode[j] == 1) v = xsw[(m * 16 + l15) * 98 + kbase[j] + poff];
      else if (kmode[j] == 2) v = 0x3F80;   // 1.0 bf16
      a1x[m][j] = (short)v;
    }
  }

  // L2 accumulators init with bias2
  f32x4 acc[8][2];
#pragma unroll
  for (int t = 0; t < 8; ++t) {
    f32x4 b2 = *(const f32x4*)(b2v + p * 128 + t * 16 + g * 4);
    acc[t][0] = b2; acc[t][1] = b2;
  }

  unsigned pk[2][8][2];   // [m][t'][b]

#define L1PH(W)                                                                   \
  {                                                                               \
    __builtin_amdgcn_s_setprio(1);                                                \
    _Pragma("unroll")                                                             \
    for (int t_ = 0; t_ < 8; ++t_) {                                              \
      f32x4 c0_ = mfma16(W[t_], a1x[0], zf);                                      \
      f32x4 c1_ = mfma16(W[t_], a1x[1], zf);                                      \
      relu_pack2(c0_, pk[0][t_][0], pk[0][t_][1]);                                \
      relu_pack2(c1_, pk[1][t_][0], pk[1][t_][1]);                                \
    }                                                                             \
    __builtin_amdgcn_s_setprio(0);                                                \
  }

#define L2PH(W, KQ)                                                               \
  {                                                                               \
    bf16x8 bA_ = BFRAG(pk[0], KQ), bB_ = BFRAG(pk[1], KQ);                        \
    __builtin_amdgcn_s_setprio(1);                                                \
    _Pragma("unroll")                                                             \
    for (int t_ = 0; t_ < 8; ++t_) {                                              \
      acc[t_][0] = mfma16(W[t_], bA_, acc[t_][0]);                                \
      acc[t_][1] = mfma16(W[t_], bB_, acc[t_][1]);                                \
    }                                                                             \
    __builtin_amdgcn_s_setprio(0);                                                \
  }

  // ---- static 25-phase schedule (even q computes wA, odd computes wB) ----
  PRE(wB, 1);  L1PH(wA);            // q0  s=0
  PRE(wA, 2);  L2PH(wB, 0);         // q1
  PRE(wB, 3);  L2PH(wA, 1);         // q2
  PRE(wA, 4);  L2PH(wB, 2);         // q3
  PRE(wB, 5);  L2PH(wA, 3);         // q4
  PRE(wA, 6);  L1PH(wB);            // q5  s=1
  PRE(wB, 7);  L2PH(wA, 0);         // q6
  PRE(wA, 8);  L2PH(wB, 1);         // q7
  PRE(wB, 9);  L2PH(wA, 2);         // q8
  PRE(wA, 10); L2PH(wB, 3);         // q9
  PRE(wB, 11); L1PH(wA);            // q10 s=2
  PRE(wA, 12); L2PH(wB, 0);         // q11
  PRE(wB, 13); L2PH(wA, 1);         // q12
  PRE(wA, 14); L2PH(wB, 2);         // q13
  PRE(wB, 15); L2PH(wA, 3);         // q14
  PRE(wA, 16); L1PH(wB);            // q15 s=3
  PRE(wB, 17); L2PH(wA, 0);         // q16
  PRE(wA, 18); L2PH(wB, 1);         // q17
  PRE(wB, 19); L2PH(wA, 2);         // q18
  PRE(wA, 20); L2PH(wB, 3);         // q19

  // L2 -> pk ; reinit acc with bias3
#pragma unroll
  for (int t = 0; t < 8; ++t) {
    f32x4 b3 = *(const f32x4*)(b3v + p * 128 + t * 16 + g * 4);
    relu_pack2(acc[t][0], pk[0][t][0], pk[0][t][1]);
    relu_pack2(acc[t][1], pk[1][t][0], pk[1][t][1]);
    acc[t][0] = b3; acc[t][1] = b3;
  }

  // L3 phases q20..23
  PRE(wB, 21); L2PH(wA, 0);         // q20
  PRE(wA, 22); L2PH(wB, 1);         // q21
  PRE(wB, 23); L2PH(wA, 2);         // q22
  PRE(wA, 24); L2PH(wB, 3);         // q23

  // L3 -> pk
#pragma unroll
  for (int t = 0; t < 8; ++t) {
    relu_pack2(acc[t][0], pk[0][t][0], pk[0][t][1]);
    relu_pack2(acc[t][1], pk[1][t][0], pk[1][t][1]);
  }

  // L4 accumulators init with bias4
  f32x4 c4[2][2];   // [nt][m]
#pragma unroll
  for (int nt = 0; nt < 2; ++nt) {
    f32x4 b4 = *(const f32x4*)(b4v + p * 32 + nt * 16 + g * 4);
    c4[nt][0] = b4; c4[nt][1] = b4;
  }

  // q24: L4 computes wA (no further prefetch)
  {
    __builtin_amdgcn_s_setprio(1);
#pragma unroll
    for (int kq = 0; kq < 4; ++kq) {
      bf16x8 bA_ = BFRAG(pk[0], kq), bB_ = BFRAG(pk[1], kq);
#pragma unroll
      for (int nt = 0; nt < 2; ++nt) {
        c4[nt][0] = mfma16(wA[nt * 4 + kq], bA_, c4[nt][0]);
        c4[nt][1] = mfma16(wA[nt * 4 + kq], bB_, c4[nt][1]);
      }
    }
    __builtin_amdgcn_s_setprio(0);
  }
#undef PRE
#undef L1PH
#undef L2PH

  // clamp and write this position's partial plane
#pragma unroll
  for (int m = 0; m < 2; ++m) {
#pragma unroll
    for (int nt = 0; nt < 2; ++nt) {
      f32x4 v;
#pragma unroll
      for (int r = 0; r < 4; ++r)
        v[r] = fminf(fmaxf(c4[nt][m][r], -1.f), CMAXF);
      *(f32x4*)(part + ((size_t)p * BATCH + R0 + m * 16 + l15) * 32 + nt * 16 + g * 4) = v;
    }
  }
}

// ---------------- head: reduce 25 partials + clipped MLP ----------------
__global__ __launch_bounds__(256) void head_kernel(
    const float* __restrict__ part,
    const float* __restrict__ fc1w, const float* __restrict__ fc1b,
    const float* __restrict__ fc2w, const float* __restrict__ fc2b,
    const float* __restrict__ fc3w, const float* __restrict__ fc3b,
    float* __restrict__ out)
{
  const int lane = threadIdx.x & 63;
  const int o = lane & 31;
  const int half = lane >> 5;
  const int wave = threadIdx.x >> 6;
  const int row = blockIdx.x * 8 + wave * 2 + half;

  float feat = 0.f;
#pragma unroll
  for (int gi = 0; gi < NPOS; ++gi)
    feat += part[((size_t)gi * BATCH + row) * 32 + o];
  feat = feat < 0.f ? 0.f : (feat > CMAXF ? CMAXF : feat);

  float a = fc1b[o];
#pragma unroll
  for (int k = 0; k < 32; ++k)
    a += __shfl(feat, k, 32) * fc1w[o * 32 + k];
  a = a < 0.f ? 0.f : (a > CMAXF ? CMAXF : a);

  float b = fc2b[o];
#pragma unroll
  for (int k = 0; k < 32; ++k)
    b += __shfl(a, k, 32) * fc2w[o * 32 + k];
  b = b < 0.f ? 0.f : (b > CMAXF ? CMAXF : b);

  float c = b * fc3w[o];
#pragma unroll
  for (int m = 16; m >= 1; m >>= 1)
    c += __shfl_xor(c, m, 32);
  if (o == 0) out[row] = c + fc3b[0];
}

extern "C" void kernel_launch(void* const* d_in, const int* in_sizes, int n_in,
                              void* d_out, int out_size, void* d_ws, size_t ws_size,
                              hipStream_t stream) {
  const float* x    = (const float*)d_in[0];
  const float* W1   = (const float*)d_in[1];
  const float* b1   = (const float*)d_in[2];
  const float* W2   = (const float*)d_in[3];
  const float* b2   = (const float*)d_in[4];
  const float* W3   = (const float*)d_in[5];
  const float* b3   = (const float*)d_in[6];
  const float* W4   = (const float*)d_in[7];
  const float* b4   = (const float*)d_in[8];
  const float* fc1w = (const float*)d_in[9];
  const float* fc1b = (const float*)d_in[10];
  const float* fc2w = (const float*)d_in[11];
  const float* fc2b = (const float*)d_in[12];
  const float* fc3w = (const float*)d_in[13];
  const float* fc3b = (const float*)d_in[14];
  float* out = (float*)d_out;

  unsigned short* wf = (unsigned short*)d_ws;
  float* part = (float*)((char*)d_ws + PART_BYTE_OFF);

  prep_kernel<<<WF_TOTAL / 1024, 256, 0, stream>>>(W1, b1, W2, W3, W4, wf);
  tower_kernel<<<6400, 64, 0, stream>>>(x, b2, b3, b4, wf, part);
  head_kernel<<<BATCH / 8, 256, 0, stream>>>(part, fc1w, fc1b, fc2w, fc2b, fc3w, fc3b, out);
}

// Round 12
// 87.192 us; speedup vs baseline: 3.7991x; 3.7991x over previous
//
#include <hip/hip_runtime.h>
#include <hip/hip_bf16.h>

// FlatConv3x3NNUE R12: R11's 25-way position parallelism (wave = (btile, position),
// M=32, reg-direct W, depth-1 wA/wB, in-register activations) with the register
// strangulation fixed: __launch_bounds__(64, 2) -> ~112 VGPR, no spill, HW occupancy
// ~4 waves/SIMD from 6400 waves.

#define BATCH 8192
#define CMAXF 0.9921875f
#define NPOS 25

// wf: bf16 [25 p][25 q][8 f][64 lane][8 j]  (8KB per phase, contiguous)
#define WF_TOTAL 2560000
#define PART_BYTE_OFF 5120000  // float [25][8192][32] partial features (26.2 MB)

using bf16x8 = __attribute__((ext_vector_type(8))) short;
using f32x4  = __attribute__((ext_vector_type(4))) float;

__device__ __forceinline__ unsigned short f2bf(float f) {
  union { float f; unsigned u; } v; v.f = f;
  unsigned u = v.u + 0x7fffu + ((v.u >> 16) & 1u);   // RNE
  return (unsigned short)(u >> 16);
}

__device__ __forceinline__ f32x4 mfma16(bf16x8 a, bf16x8 b, f32x4 c) {
  return __builtin_amdgcn_mfma_f32_16x16x32_bf16(a, b, c, 0, 0, 0);
}

// relu + pack f32x4 -> 2 u32 of bf16 pairs
__device__ __forceinline__ void relu_pack2(f32x4 v, unsigned& lo, unsigned& hi) {
  union { __hip_bfloat162 h; unsigned u; } a_, b_;
  a_.h = __float22bfloat162_rn(make_float2(fmaxf(v[0], 0.f), fmaxf(v[1], 0.f)));
  b_.h = __float22bfloat162_rn(make_float2(fmaxf(v[2], 0.f), fmaxf(v[3], 0.f)));
  lo = a_.u; hi = b_.u;
}

// ---------------- prep: weights -> bf16 [p][q][f][lane][j] (same as R5-R11) ------------
__global__ __launch_bounds__(256) void prep_kernel(
    const float* __restrict__ W1, const float* __restrict__ b1,
    const float* __restrict__ W2, const float* __restrict__ W3,
    const float* __restrict__ W4, unsigned short* __restrict__ wf)
{
  int e4 = (blockIdx.x * 256 + threadIdx.x) * 4;
  if (e4 >= WF_TOTAL) return;
  const int j0 = e4 & 7;
  const int l = (e4 >> 3) & 63;
  const int f = (e4 >> 9) & 7;
  const int pq = e4 >> 12;
  const int p = pq / 25, q = pq - p * 25;
  const int g = l >> 4, l15 = l & 15;
  unsigned short vv[4];
#pragma unroll
  for (int i = 0; i < 4; ++i) {
    int j = j0 + i;
    float val = 0.f;
    if (q < 20) {
      int s = q / 5, rem = q - s * 5;
      if (rem == 0) {              // L1(s): k = g*8+j (18 real, 18=bias)
        int o = f * 16 + l15;
        int kk = g * 8 + j;
        if (kk < 18) {
          int c = (kk >= 9) ? 1 : 0;
          int rr = kk - c * 9;
          int py = rr / 3, px = rr - py * 3;
          int si = s >> 1, sj = s & 1;
          int di = py - si, dj = px - sj;
          if (di >= 0 && di < 2 && dj >= 0 && dj < 2)
            val = W1[((p * 128 + o) * 2 + c) * 4 + di * 2 + dj];
        } else if (kk == 18) {
          val = b1[p * 128 + o];
        }
      } else {                     // L2(s,kq): c = 32kq + 16(j>>2) + 4g + (j&3)
        int kq = rem - 1;
        int o = f * 16 + l15;
        int c = kq * 32 + ((j >> 2) << 4) + g * 4 + (j & 3);
        val = W2[((p * 128 + o) * 128 + c) * 4 + s];
      }
    } else if (q < 24) {           // L3(kq)
      int kq = q - 20;
      int o = f * 16 + l15;
      int c = kq * 32 + ((j >> 2) << 4) + g * 4 + (j & 3);
      val = W3[(p * 128 + o) * 128 + c];
    } else {                       // L4: f = nt*4+kq
      int nt = f >> 2, kq = f & 3;
      int o = nt * 16 + l15;
      int c = kq * 32 + ((j >> 2) << 4) + g * 4 + (j & 3);
      val = W4[(p * 32 + o) * 128 + c];
    }
    vv[i] = f2bf(val);
  }
  ushort4 st; st.x = vv[0]; st.y = vv[1]; st.z = vv[2]; st.w = vv[3];
  *(ushort4*)(wf + e4) = st;
}

// B-frag (bf16x8) from 4 packed u32
#define BFRAG(pkm, kq) ({                                        \
  union { unsigned u[4]; bf16x8 v; } _bf;                        \
  _bf.u[0] = pkm[2*(kq)][0];   _bf.u[1] = pkm[2*(kq)][1];        \
  _bf.u[2] = pkm[2*(kq)+1][0]; _bf.u[3] = pkm[2*(kq)+1][1];      \
  _bf.v; })

// ---------------- tower: 1 wave/block, 1 position/wave, M=32, no barriers -------------
__global__ __launch_bounds__(64, 2) void tower_kernel(
    const float* __restrict__ x,
    const float* __restrict__ b2v, const float* __restrict__ b3v,
    const float* __restrict__ b4v,
    const unsigned short* __restrict__ wf, float* __restrict__ part)
{
  __shared__ __align__(16) unsigned short xsw[32 * 98];

  const int l = threadIdx.x;
  const int l15 = l & 15;
  const int g = l >> 4;

  // XCD-contiguous bijective remap: 6400 = 8 * 800; p varies fastest within an XCD
  int bid = blockIdx.x;
  int lin = (bid & 7) * 800 + (bid >> 3);
  int btile = lin / 25;           // 0..255
  const int p = lin - btile * 25; // 0..24
  const int R0 = btile * 32;

  bf16x8 wA[8], wB[8];

#define PRE(DST, QN)                                                              \
  {                                                                               \
    const unsigned short* s_ = wf + ((size_t)(p * 25 + (QN)) * 8) * 512 + l * 8;  \
    _Pragma("unroll")                                                             \
    for (int f_ = 0; f_ < 8; ++f_) DST[f_] = *(const bf16x8*)(s_ + f_ * 512);     \
  }

  // issue first W loads before xs fill so they are in flight during staging
  PRE(wA, 0);

  for (int idx = l; idx < 32 * 98; idx += 64)
    xsw[idx] = f2bf(x[(size_t)R0 * 98 + idx]);
  __syncthreads();

  // per-lane K decode for L1 B-fragment
  int kbase[8]; int kmode[8];   // 0: zero, 1: xs, 2: const one (bias)
#pragma unroll
  for (int j = 0; j < 8; ++j) {
    int k = g * 8 + j;
    if (k < 18) {
      int c = (k >= 9) ? 1 : 0;
      int rr = k - c * 9;
      int py = rr / 3, px = rr - (rr / 3) * 3;
      kbase[j] = c * 49 + py * 7 + px;
      kmode[j] = 1;
    } else { kbase[j] = 0; kmode[j] = (k == 18) ? 2 : 0; }
  }

  const f32x4 zf = {0.f, 0.f, 0.f, 0.f};
  const int y0 = p / 5;
  const int x0 = p - y0 * 5;
  const int poff = y0 * 7 + x0;

  // L1 B-fragments (both batch tiles) from xs
  bf16x8 a1x[2];
#pragma unroll
  for (int m = 0; m < 2; ++m) {
#pragma unroll
    for (int j = 0; j < 8; ++j) {
      unsigned short v = 0;
      if (kmode[j] == 1) v = xsw[(m * 16 + l15) * 98 + kbase[j] + poff];
      else if (kmode[j] == 2) v = 0x3F80;   // 1.0 bf16
      a1x[m][j] = (short)v;
    }
  }

  // L2 accumulators init with bias2
  f32x4 acc[8][2];
#pragma unroll
  for (int t = 0; t < 8; ++t) {
    f32x4 b2 = *(const f32x4*)(b2v + p * 128 + t * 16 + g * 4);
    acc[t][0] = b2; acc[t][1] = b2;
  }

  unsigned pk[2][8][2];   // [m][t'][b]

#define L1PH(W)                                                                   \
  {                                                                               \
    __builtin_amdgcn_s_setprio(1);                                                \
    _Pragma("unroll")                                                             \
    for (int t_ = 0; t_ < 8; ++t_) {                                              \
      f32x4 c0_ = mfma16(W[t_], a1x[0], zf);                                      \
      f32x4 c1_ = mfma16(W[t_], a1x[1], zf);                                      \
      relu_pack2(c0_, pk[0][t_][0], pk[0][t_][1]);                                \
      relu_pack2(c1_, pk[1][t_][0], pk[1][t_][1]);                                \
    }                                                                             \
    __builtin_amdgcn_s_setprio(0);                                                \
  }

#define L2PH(W, KQ)                                                               \
  {                                                                               \
    bf16x8 bA_ = BFRAG(pk[0], KQ), bB_ = BFRAG(pk[1], KQ);                        \
    __builtin_amdgcn_s_setprio(1);                                                \
    _Pragma("unroll")                                                             \
    for (int t_ = 0; t_ < 8; ++t_) {                                              \
      acc[t_][0] = mfma16(W[t_], bA_, acc[t_][0]);                                \
      acc[t_][1] = mfma16(W[t_], bB_, acc[t_][1]);                                \
    }                                                                             \
    __builtin_amdgcn_s_setprio(0);                                                \
  }

  // ---- static 25-phase schedule (even q computes wA, odd computes wB) ----
  PRE(wB, 1);  L1PH(wA);            // q0  s=0
  PRE(wA, 2);  L2PH(wB, 0);         // q1
  PRE(wB, 3);  L2PH(wA, 1);         // q2
  PRE(wA, 4);  L2PH(wB, 2);         // q3
  PRE(wB, 5);  L2PH(wA, 3);         // q4
  PRE(wA, 6);  L1PH(wB);            // q5  s=1
  PRE(wB, 7);  L2PH(wA, 0);         // q6
  PRE(wA, 8);  L2PH(wB, 1);         // q7
  PRE(wB, 9);  L2PH(wA, 2);         // q8
  PRE(wA, 10); L2PH(wB, 3);         // q9
  PRE(wB, 11); L1PH(wA);            // q10 s=2
  PRE(wA, 12); L2PH(wB, 0);         // q11
  PRE(wB, 13); L2PH(wA, 1);         // q12
  PRE(wA, 14); L2PH(wB, 2);         // q13
  PRE(wB, 15); L2PH(wA, 3);         // q14
  PRE(wA, 16); L1PH(wB);            // q15 s=3
  PRE(wB, 17); L2PH(wA, 0);         // q16
  PRE(wA, 18); L2PH(wB, 1);         // q17
  PRE(wB, 19); L2PH(wA, 2);         // q18
  PRE(wA, 20); L2PH(wB, 3);         // q19

  // L2 -> pk ; reinit acc with bias3
#pragma unroll
  for (int t = 0; t < 8; ++t) {
    f32x4 b3 = *(const f32x4*)(b3v + p * 128 + t * 16 + g * 4);
    relu_pack2(acc[t][0], pk[0][t][0], pk[0][t][1]);
    relu_pack2(acc[t][1], pk[1][t][0], pk[1][t][1]);
    acc[t][0] = b3; acc[t][1] = b3;
  }

  // L3 phases q20..23
  PRE(wB, 21); L2PH(wA, 0);         // q20
  PRE(wA, 22); L2PH(wB, 1);         // q21
  PRE(wB, 23); L2PH(wA, 2);         // q22
  PRE(wA, 24); L2PH(wB, 3);         // q23

  // L3 -> pk
#pragma unroll
  for (int t = 0; t < 8; ++t) {
    relu_pack2(acc[t][0], pk[0][t][0], pk[0][t][1]);
    relu_pack2(acc[t][1], pk[1][t][0], pk[1][t][1]);
  }

  // L4 accumulators init with bias4
  f32x4 c4[2][2];   // [nt][m]
#pragma unroll
  for (int nt = 0; nt < 2; ++nt) {
    f32x4 b4 = *(const f32x4*)(b4v + p * 32 + nt * 16 + g * 4);
    c4[nt][0] = b4; c4[nt][1] = b4;
  }

  // q24: L4 computes wA (no further prefetch)
  {
    __builtin_amdgcn_s_setprio(1);
#pragma unroll
    for (int kq = 0; kq < 4; ++kq) {
      bf16x8 bA_ = BFRAG(pk[0], kq), bB_ = BFRAG(pk[1], kq);
#pragma unroll
      for (int nt = 0; nt < 2; ++nt) {
        c4[nt][0] = mfma16(wA[nt * 4 + kq], bA_, c4[nt][0]);
        c4[nt][1] = mfma16(wA[nt * 4 + kq], bB_, c4[nt][1]);
      }
    }
    __builtin_amdgcn_s_setprio(0);
  }
#undef PRE
#undef L1PH
#undef L2PH

  // clamp and write this position's partial plane
#pragma unroll
  for (int m = 0; m < 2; ++m) {
#pragma unroll
    for (int nt = 0; nt < 2; ++nt) {
      f32x4 v;
#pragma unroll
      for (int r = 0; r < 4; ++r)
        v[r] = fminf(fmaxf(c4[nt][m][r], -1.f), CMAXF);
      *(f32x4*)(part + ((size_t)p * BATCH + R0 + m * 16 + l15) * 32 + nt * 16 + g * 4) = v;
    }
  }
}

// ---------------- head: reduce 25 partials + clipped MLP ----------------
__global__ __launch_bounds__(256) void head_kernel(
    const float* __restrict__ part,
    const float* __restrict__ fc1w, const float* __restrict__ fc1b,
    const float* __restrict__ fc2w, const float* __restrict__ fc2b,
    const float* __restrict__ fc3w, const float* __restrict__ fc3b,
    float* __restrict__ out)
{
  const int lane = threadIdx.x & 63;
  const int o = lane & 31;
  const int half = lane >> 5;
  const int wave = threadIdx.x >> 6;
  const int row = blockIdx.x * 8 + wave * 2 + half;

  float feat = 0.f;
#pragma unroll
  for (int gi = 0; gi < NPOS; ++gi)
    feat += part[((size_t)gi * BATCH + row) * 32 + o];
  feat = feat < 0.f ? 0.f : (feat > CMAXF ? CMAXF : feat);

  float a = fc1b[o];
#pragma unroll
  for (int k = 0; k < 32; ++k)
    a += __shfl(feat, k, 32) * fc1w[o * 32 + k];
  a = a < 0.f ? 0.f : (a > CMAXF ? CMAXF : a);

  float b = fc2b[o];
#pragma unroll
  for (int k = 0; k < 32; ++k)
    b += __shfl(a, k, 32) * fc2w[o * 32 + k];
  b = b < 0.f ? 0.f : (b > CMAXF ? CMAXF : b);

  float c = b * fc3w[o];
#pragma unroll
  for (int m = 16; m >= 1; m >>= 1)
    c += __shfl_xor(c, m, 32);
  if (o == 0) out[row] = c + fc3b[0];
}

extern "C" void kernel_launch(void* const* d_in, const int* in_sizes, int n_in,
                              void* d_out, int out_size, void* d_ws, size_t ws_size,
                              hipStream_t stream) {
  const float* x    = (const float*)d_in[0];
  const float* W1   = (const float*)d_in[1];
  const float* b1   = (const float*)d_in[2];
  const float* W2   = (const float*)d_in[3];
  const float* b2   = (const float*)d_in[4];
  const float* W3   = (const float*)d_in[5];
  const float* b3   = (const float*)d_in[6];
  const float* W4   = (const float*)d_in[7];
  const float* b4   = (const float*)d_in[8];
  const float* fc1w = (const float*)d_in[9];
  const float* fc1b = (const float*)d_in[10];
  const float* fc2w = (const float*)d_in[11];
  const float* fc2b = (const float*)d_in[12];
  const float* fc3w = (const float*)d_in[13];
  const float* fc3b = (const float*)d_in[14];
  float* out = (float*)d_out;

  unsigned short* wf = (unsigned short*)d_ws;
  float* part = (float*)((char*)d_ws + PART_BYTE_OFF);

  prep_kernel<<<WF_TOTAL / 1024, 256, 0, stream>>>(W1, b1, W2, W3, W4, wf);
  tower_kernel<<<6400, 64, 0, stream>>>(x, b2, b3, b4, wf, part);
  head_kernel<<<BATCH / 8, 256, 0, stream>>>(part, fc1w, fc1b, fc2w, fc2b, fc3w, fc3b, out);
}